// Round 4
// baseline (253.014 us; speedup 1.0000x reference)
//
#include <hip/hip_runtime.h>
#include <hip/hip_bf16.h>

typedef __hip_bfloat16 bf16;
typedef short short8 __attribute__((ext_vector_type(8)));
typedef float floatx4 __attribute__((ext_vector_type(4)));
typedef unsigned uintx4 __attribute__((ext_vector_type(4)));
typedef unsigned short ushort;

#define MFMA __builtin_amdgcn_mfma_f32_16x16x32_bf16

#define BATCH 4
#define SEQ   1024
#define DIM   1024
#define HEADS 16
#define HD    64
#define RS    72    // attn LDS row stride in shorts (BK=64 + 8 pad)
#define BK    128   // GEMM K-tile (r4: halves the 16-iter serial chain to 8)
#define RSK   136   // GEMM LDS row stride in shorts (BK + 8 pad)
#define NKT   (DIM / BK)   // 8 K-iterations

// scores = -(sq_i - 2 q.k + sq_j)*0.125. Analytic max = self-score (dist=0),
// so p = exp(0.25*dot - 0.125*sq_j - 0.125*sq_i) = exp(-dist^2/8) in (0,1]
// is the EXACT softmax numerator — no running max needed.
//
// LESSON LEDGER:
// r1: occupancy is NOT the limiter (2x occupancy, +16% time tracking +33%
//     staging rows). GEMMs are chain/staging bound.
// r2: cooperative grid.sync fusion = 383us (grid-wide sync at 2 blk/CU +
//     L2 flush at sync). Dead end.
// r3: nontemporal stores neutral -> dirty-L2 probe theory dead.
// r0-r3 synthesis: gemm<0> does 2x FLOPs & 2x staged bytes of gemm<1> in
//     EQUAL time -> both bound by the 16-iteration serial K-chain (exposed
//     load latency + 2 barrier drains per iter; compiler sinks "prefetch"
//     loads near use — VGPR_Count=64 proves registers aren't held).
// r4 (this): BK 64->128: 8 iterations, same total staged bytes. Chain halves.

__device__ __forceinline__ float b2f(ushort u) {
    union { unsigned i; float f; } x; x.i = (unsigned)u << 16; return x.f;
}
__device__ __forceinline__ ushort f2b(float f) {   // RTNE
    union { float f; unsigned i; } x; x.f = f;
    return (ushort)((x.i + 0x7FFFu + ((x.i >> 16) & 1u)) >> 16);
}

__device__ __forceinline__ void nts16(void* p, uint4 v) {
    uintx4 x; x.x = v.x; x.y = v.y; x.z = v.z; x.w = v.w;
    __builtin_nontemporal_store(x, (uintx4*)p);
}
__device__ __forceinline__ void nts16f(void* p, float4 v) {
    floatx4 x; x.x = v.x; x.y = v.y; x.z = v.z; x.w = v.w;
    __builtin_nontemporal_store(x, (floatx4*)p);
}
__device__ __forceinline__ void nts2(ushort* p, ushort v) {
    __builtin_nontemporal_store(v, p);
}

// 8 fp32 (two uint4) -> 8 bf16 via hw packed cvt (v_cvt_pk_bf16_f32, RTNE)
__device__ __forceinline__ short8 cvt8(uint4 a, uint4 b) {
    const float* f0 = (const float*)&a;
    const float* f1 = (const float*)&b;
    union { __hip_bfloat162 h; unsigned u; } c0, c1, c2, c3;
    float2 p;
    p.x = f0[0]; p.y = f0[1]; c0.h = __float22bfloat162_rn(p);
    p.x = f0[2]; p.y = f0[3]; c1.h = __float22bfloat162_rn(p);
    p.x = f1[0]; p.y = f1[1]; c2.h = __float22bfloat162_rn(p);
    p.x = f1[2]; p.y = f1[3]; c3.h = __float22bfloat162_rn(p);
    short8 s;
    unsigned* su = (unsigned*)&s;
    su[0] = c0.u; su[1] = c1.u; su[2] = c2.u; su[3] = c3.u;
    return s;
}

// ---------------------------------------------------------------------------
// MFMA GEMM core. C = A @ W_f32^T + bias_f32. 128x64 tile, BK=128 (8-iter
// chain), register prefetch, packed-cvt staging.
// OUT=0: A = x fp32 (converted during staging). Fused Q+V: blockIdx.x<16 ->
//        Q bf16 [bh,n,d]; else V^T bf16 [bh,d,n]. LDS-transposed writes.
// OUT=1: A = Oh bf16; LDS-transpose epilogue, full-line fp32 writes.
// ---------------------------------------------------------------------------
template<int OUT>
__global__ __launch_bounds__(256)
void gemm_core(const void* __restrict__ Av,
               const float* __restrict__ W0, const float* __restrict__ b0,
               const float* __restrict__ W1, const float* __restrict__ b1,
               ushort* __restrict__ Qd, ushort* __restrict__ Vd,
               float* __restrict__ Fd)
{
    constexpr int AF32 = (OUT == 0) ? 1 : 0;
    __shared__ __align__(16) ushort SMEM[128 * RSK + 64 * RSK];   // 52.2 KB
    ushort* Asm = SMEM;
    ushort* Bsm = SMEM + 128 * RSK;

    const int t = threadIdx.x;
    const int w = t >> 6, lane = t & 63;
    const int lr = lane & 15, quad = lane >> 4;
    const int isV = (!OUT) && (blockIdx.x >= 16);
    const int n0 = (blockIdx.x & 15) * 64;
    const int m0 = blockIdx.y * 128;
    const float* __restrict__ W    = isV ? W1 : W0;
    const float* __restrict__ bias = isV ? b1 : b0;
    const int mw = (w >> 1) * 64, nw = (w & 1) * 32;
    // staging geometry: 16 threads cover one 128-col row (8 elems each)
    const int ar = t >> 4, ac8 = (t & 15) * 8;

    uint4 apre[AF32 ? 16 : 8], wpre[8];
    #pragma unroll
    for (int c = 0; c < 8; ++c) {
        if (AF32) {
            const float* ap = (const float*)Av + (size_t)(m0 + c * 16 + ar) * DIM + ac8;
            apre[2 * c]     = *(const uint4*)ap;
            apre[2 * c + 1] = *(const uint4*)(ap + 4);
        } else {
            apre[c] = *(const uint4*)((const ushort*)Av + (size_t)(m0 + c * 16 + ar) * DIM + ac8);
        }
    }
    #pragma unroll
    for (int c = 0; c < 4; ++c) {
        const float* wp = W + (size_t)(n0 + c * 16 + ar) * DIM + ac8;
        wpre[2 * c]     = *(const uint4*)wp;
        wpre[2 * c + 1] = *(const uint4*)(wp + 4);
    }

    floatx4 acc[4][2];
    const floatx4 fz = {0.f, 0.f, 0.f, 0.f};
    #pragma unroll
    for (int i = 0; i < 4; ++i)
        #pragma unroll
        for (int j = 0; j < 2; ++j) acc[i][j] = fz;

    for (int kt = 0; kt < NKT; ++kt) {
        #pragma unroll
        for (int c = 0; c < 8; ++c) {
            if (AF32) {
                *(short8*)&Asm[(c * 16 + ar) * RSK + ac8] = cvt8(apre[2 * c], apre[2 * c + 1]);
            } else {
                *(uint4*)&Asm[(c * 16 + ar) * RSK + ac8] = apre[c];
            }
        }
        #pragma unroll
        for (int c = 0; c < 4; ++c)
            *(short8*)&Bsm[(c * 16 + ar) * RSK + ac8] = cvt8(wpre[2 * c], wpre[2 * c + 1]);
        __syncthreads();
        if (kt < NKT - 1) {
            const int k0 = (kt + 1) * BK;
            #pragma unroll
            for (int c = 0; c < 8; ++c) {
                if (AF32) {
                    const float* ap = (const float*)Av + (size_t)(m0 + c * 16 + ar) * DIM + k0 + ac8;
                    apre[2 * c]     = *(const uint4*)ap;
                    apre[2 * c + 1] = *(const uint4*)(ap + 4);
                } else {
                    apre[c] = *(const uint4*)((const ushort*)Av + (size_t)(m0 + c * 16 + ar) * DIM + k0 + ac8);
                }
            }
            #pragma unroll
            for (int c = 0; c < 4; ++c) {
                const float* wp = W + (size_t)(n0 + c * 16 + ar) * DIM + k0 + ac8;
                wpre[2 * c]     = *(const uint4*)wp;
                wpre[2 * c + 1] = *(const uint4*)(wp + 4);
            }
        }
        // 4 k-slices of 32; fragments loaded per-slice to cap live VGPRs
        #pragma unroll
        for (int ks = 0; ks < 4; ++ks) {
            short8 af[4], bfx[2];
            #pragma unroll
            for (int tm = 0; tm < 4; ++tm)
                af[tm] = *(const short8*)&Asm[(mw + tm * 16 + lr) * RSK + ks * 32 + quad * 8];
            #pragma unroll
            for (int tn = 0; tn < 2; ++tn)
                bfx[tn] = *(const short8*)&Bsm[(nw + tn * 16 + lr) * RSK + ks * 32 + quad * 8];
            #pragma unroll
            for (int tm = 0; tm < 4; ++tm)
                #pragma unroll
                for (int tn = 0; tn < 2; ++tn)
                    acc[tm][tn] = MFMA(af[tm], bfx[tn], acc[tm][tn], 0, 0, 0);
        }
        __syncthreads();   // also protects SMEM reuse by the epilogue
    }

    // epilogue: D layout col=lane&15, row=quad*4+reg [verified m89/m91]
    if (OUT) {
        float* TF = (float*)SMEM;
        #pragma unroll
        for (int pass = 0; pass < 2; ++pass) {
            __syncthreads();
            if ((w >> 1) == pass) {
                #pragma unroll
                for (int tn = 0; tn < 2; ++tn) {
                    const float bval = bias[n0 + nw + tn * 16 + lr];
                    #pragma unroll
                    for (int tm = 0; tm < 4; ++tm)
                        #pragma unroll
                        for (int r = 0; r < 4; ++r)
                            TF[(tm * 16 + quad * 4 + r) * 68 + nw + tn * 16 + lr] =
                                acc[tm][tn][r] + bval;
                }
            }
            __syncthreads();
            #pragma unroll
            for (int it = 0; it < 4; ++it) {
                const int cid = it * 256 + t;
                const int row = cid >> 4, c4 = (cid & 15) * 4;
                nts16f(Fd + (size_t)(m0 + pass * 64 + row) * DIM + n0 + c4,
                       *(const float4*)&TF[row * 68 + c4]);
            }
        }
        return;
    }

    const int bb = m0 >> 10, ii0 = m0 & 1023;
    const int head = blockIdx.x & 15;
    const int bh = bb * HEADS + head;
    if (!isV) {
        #pragma unroll
        for (int tn = 0; tn < 2; ++tn) {
            const float bval = bias[n0 + nw + tn * 16 + lr];
            #pragma unroll
            for (int tm = 0; tm < 4; ++tm)
                #pragma unroll
                for (int r = 0; r < 4; ++r)
                    SMEM[(mw + tm * 16 + quad * 4 + r) * 80 + nw + tn * 16 + lr] =
                        f2b(acc[tm][tn][r] + bval);
        }
        __syncthreads();
        #pragma unroll
        for (int it = 0; it < 4; ++it) {
            const int cid = it * 256 + t;
            const int row = cid >> 3, col8 = (cid & 7) * 8;
            nts16(Qd + ((size_t)bh * SEQ + ii0 + row) * HD + col8,
                  *(const uint4*)&SMEM[row * 80 + col8]);
        }
    } else {
        #pragma unroll
        for (int tn = 0; tn < 2; ++tn) {
            const float bval = bias[n0 + nw + tn * 16 + lr];
            #pragma unroll
            for (int tm = 0; tm < 4; ++tm)
                #pragma unroll
                for (int r = 0; r < 4; ++r)
                    SMEM[(nw + tn * 16 + lr) * 144 + mw + tm * 16 + quad * 4 + r] =
                        f2b(acc[tm][tn][r] + bval);
        }
        __syncthreads();
        #pragma unroll
        for (int it = 0; it < 4; ++it) {
            const int cid = it * 256 + t;
            const int row = cid >> 4, col8 = (cid & 15) * 8;
            nts16(Vd + ((size_t)bh * HD + row) * SEQ + ii0 + col8,
                  *(const uint4*)&SMEM[row * 144 + col8]);
        }
    }
}

// ---------------------------------------------------------------------------
// MFMA flash L2-attention, i-tile 128 (r0-proven, unchanged this round).
// 512 blocks, XCD swizzle bh=id&63. Q bf16 [bh][n][64], Vt bf16 [bh][d][n].
// O bf16 [b][n][h*d].
// ---------------------------------------------------------------------------
__global__ __launch_bounds__(256)
void attn_mfma(const ushort* __restrict__ Q, const ushort* __restrict__ Vt,
               ushort* __restrict__ O)
{
    __shared__ __align__(16) ushort Ps[128 * RS];   // Q stage, then P [i][j]
    __shared__ __align__(16) ushort Ks[64 * RS];
    __shared__ __align__(16) ushort Vs[64 * RS];
    __shared__ float sqq[128], sqk[64];

    const int t = threadIdx.x;
    const int w = t >> 6, lane = t & 63;
    const int lr = lane & 15, quad = lane >> 4;
    const int id = blockIdx.x;
    const int bh = id & 63;            // 512 blocks: 8 i-blocks x 64 bh
    const int i0 = (id >> 6) * 128;
    const ushort* __restrict__ Qp = Q  + (size_t)bh * SEQ * HD;
    const ushort* __restrict__ Vp = Vt + (size_t)bh * HD * SEQ;

    const int sr = t >> 3, sc8 = (t & 7) * 8;

    #pragma unroll
    for (int it = 0; it < 4; ++it) {
        const int cid = it * 256 + t;
        const int r = cid >> 3, c8 = (cid & 7) * 8;
        *(uint4*)&Ps[r * RS + c8] = *(const uint4*)(Qp + (size_t)(i0 + r) * HD + c8);
    }
    __syncthreads();

    {
        const int qsub = quad & 1, half = quad >> 1;
        const int qr = w * 32 + qsub * 16 + lr, ch = half * 32;
        float s = 0.f;
        #pragma unroll
        for (int cc = 0; cc < 4; ++cc) {
            uint4 k = *(const uint4*)&Ps[qr * RS + ch + cc * 8];
            const ushort* u = (const ushort*)&k;
            #pragma unroll
            for (int e = 0; e < 8; ++e) { float f = b2f(u[e]); s += f * f; }
        }
        s += __shfl_xor(s, 32);
        if (half == 0) sqq[qr] = s;
    }
    __syncthreads();

    short8 qa[2][2];
    #pragma unroll
    for (int tm = 0; tm < 2; ++tm)
        #pragma unroll
        for (int ks = 0; ks < 2; ++ks)
            qa[tm][ks] = *(const short8*)&Ps[(w * 32 + tm * 16 + lr) * RS + ks * 32 + quad * 8];
    float sqi[2][4];
    #pragma unroll
    for (int tm = 0; tm < 2; ++tm)
        #pragma unroll
        for (int r = 0; r < 4; ++r)
            sqi[tm][r] = sqq[w * 32 + tm * 16 + quad * 4 + r];

    floatx4 oacc[2][4];
    const floatx4 fz = {0.f, 0.f, 0.f, 0.f};
    float lrow[2][4] = {};
    #pragma unroll
    for (int tm = 0; tm < 2; ++tm)
        #pragma unroll
        for (int td = 0; td < 4; ++td) oacc[tm][td] = fz;

    for (int jt = 0; jt < 16; ++jt) {
        const int j0 = jt * 64;
        __syncthreads();
        #pragma unroll
        for (int it = 0; it < 2; ++it) {
            const int r = it * 32 + sr;
            *(uint4*)&Ks[r * RS + sc8] = *(const uint4*)(Qp + (size_t)(j0 + r) * HD + sc8);
            *(uint4*)&Vs[r * RS + sc8] = *(const uint4*)(Vp + (size_t)r * SEQ + j0 + sc8);
        }
        __syncthreads();

        {
            const int jr = w * 16 + lr, ch = quad * 16;
            uint4 k1 = *(const uint4*)&Ks[jr * RS + ch];
            uint4 k2 = *(const uint4*)&Ks[jr * RS + ch + 8];
            const ushort* u1 = (const ushort*)&k1;
            const ushort* u2 = (const ushort*)&k2;
            float s = 0.f;
            #pragma unroll
            for (int cc = 0; cc < 8; ++cc) {
                float f1 = b2f(u1[cc]), f2 = b2f(u2[cc]);
                s += f1 * f1 + f2 * f2;
            }
            s += __shfl_xor(s, 16);
            s += __shfl_xor(s, 32);
            if (quad == 0) sqk[jr] = s;
        }
        __syncthreads();

        float sq4[4];
        #pragma unroll
        for (int tn = 0; tn < 4; ++tn) sq4[tn] = sqk[tn * 16 + lr];

        short8 kb[4][2];
        #pragma unroll
        for (int tn = 0; tn < 4; ++tn)
            #pragma unroll
            for (int ks = 0; ks < 2; ++ks)
                kb[tn][ks] = *(const short8*)&Ks[(tn * 16 + lr) * RS + ks * 32 + quad * 8];

        #pragma unroll
        for (int tm = 0; tm < 2; ++tm) {
            floatx4 sacc[4];
            #pragma unroll
            for (int tn = 0; tn < 4; ++tn) {
                floatx4 a = MFMA(qa[tm][0], kb[tn][0], fz, 0, 0, 0);
                sacc[tn]  = MFMA(qa[tm][1], kb[tn][1], a, 0, 0, 0);
            }
            float sc[4][4];
            #pragma unroll
            for (int tn = 0; tn < 4; ++tn) {
                const float msq = -0.125f * sq4[tn];
                #pragma unroll
                for (int r = 0; r < 4; ++r)
                    sc[tn][r] = __expf(0.25f * sacc[tn][r] + msq - 0.125f * sqi[tm][r]);
            }
            #pragma unroll
            for (int r = 0; r < 4; ++r)
                lrow[tm][r] += sc[0][r] + sc[1][r] + sc[2][r] + sc[3][r];
            #pragma unroll
            for (int tp = 0; tp < 2; ++tp)
                #pragma unroll
                for (int r = 0; r < 4; ++r) {
                    float2 fp; fp.x = sc[2 * tp][r]; fp.y = sc[2 * tp + 1][r];
                    union { __hip_bfloat162 h; unsigned u; } cv;
                    cv.h = __float22bfloat162_rn(fp);
                    const int rowb = (w * 32 + tm * 16 + quad * 4 + r) * RS + lr;
                    Ps[rowb + (2 * tp) * 16]     = (ushort)(cv.u & 0xffffu);
                    Ps[rowb + (2 * tp + 1) * 16] = (ushort)(cv.u >> 16);
                }
        }
        __syncthreads();   // P stores visible before PV fragment reads

        short8 pa[2][2], vb[4][2];
        #pragma unroll
        for (int tm = 0; tm < 2; ++tm)
            #pragma unroll
            for (int ks = 0; ks < 2; ++ks)
                pa[tm][ks] = *(const short8*)&Ps[(w * 32 + tm * 16 + lr) * RS + ks * 32 + quad * 8];
        #pragma unroll
        for (int td = 0; td < 4; ++td)
            #pragma unroll
            for (int ks = 0; ks < 2; ++ks)
                vb[td][ks] = *(const short8*)&Vs[(td * 16 + lr) * RS + ks * 32 + quad * 8];
        #pragma unroll
        for (int tm = 0; tm < 2; ++tm)
            #pragma unroll
            for (int td = 0; td < 4; ++td) {
                oacc[tm][td] = MFMA(pa[tm][0], vb[td][0], oacc[tm][td], 0, 0, 0);
                oacc[tm][td] = MFMA(pa[tm][1], vb[td][1], oacc[tm][td], 0, 0, 0);
            }
    }

    const int bb = bh >> 4, head = bh & 15;
    #pragma unroll
    for (int tm = 0; tm < 2; ++tm)
        #pragma unroll
        for (int r = 0; r < 4; ++r) {
            float l = lrow[tm][r];
            l += __shfl_xor(l, 1);
            l += __shfl_xor(l, 2);
            l += __shfl_xor(l, 4);
            l += __shfl_xor(l, 8);
            const float inv = 1.f / l;
            const int row = i0 + w * 32 + tm * 16 + quad * 4 + r;
            #pragma unroll
            for (int td = 0; td < 4; ++td) {
                nts2(O + (size_t)(bb * SEQ + row) * DIM + head * HD + td * 16 + lr,
                     f2b(oacc[tm][td][r] * inv));
            }
        }
}

extern "C" void kernel_launch(void* const* d_in, const int* in_sizes, int n_in,
                              void* d_out, int out_size, void* d_ws, size_t ws_size,
                              hipStream_t stream)
{
    const float* x  = (const float*)d_in[0];
    const float* Wq = (const float*)d_in[1];
    const float* bq = (const float*)d_in[2];
    const float* Wv = (const float*)d_in[3];
    const float* bv = (const float*)d_in[4];
    const float* Wo = (const float*)d_in[5];
    const float* bo = (const float*)d_in[6];

    // d_ws (proven 24 MB): Qh 8MB | Vt 8MB | Oh 8MB
    ushort* Qh = (ushort*)d_ws;
    ushort* Vt = Qh + (size_t)BATCH * HEADS * SEQ * HD;
    ushort* Oh = Vt + (size_t)BATCH * HEADS * SEQ * HD;

    gemm_core<0><<<dim3(32, 32), 256, 0, stream>>>(x, Wq, bq, Wv, bv, Qh, Vt, nullptr);
    attn_mfma<<<512, 256, 0, stream>>>(Qh, Vt, Oh);
    gemm_core<1><<<dim3(16, 32), 256, 0, stream>>>(Oh, Wo, bo, nullptr, nullptr,
                                                   nullptr, nullptr, (float*)d_out);
}

// Round 5
// 219.595 us; speedup vs baseline: 1.1522x; 1.1522x over previous
//
#include <hip/hip_runtime.h>
#include <hip/hip_bf16.h>

typedef __hip_bfloat16 bf16;
typedef short short8 __attribute__((ext_vector_type(8)));
typedef float floatx4 __attribute__((ext_vector_type(4)));
typedef unsigned uintx4 __attribute__((ext_vector_type(4)));
typedef unsigned short ushort;

#define MFMA __builtin_amdgcn_mfma_f32_16x16x32_bf16

#define BATCH 4
#define SEQ   1024
#define DIM   1024
#define HEADS 16
#define HD    64
#define RS    72    // attn LDS row stride in shorts (BK=64 + 8 pad)
#define BK    128   // GEMM K-tile (8-iter serial chain)
#define RSK   136   // GEMM LDS row stride in shorts (BK + 8 pad)
#define NKT   (DIM / BK)   // 8 K-iterations

// scores = -(sq_i - 2 q.k + sq_j)*0.125. Analytic max = self-score (dist=0),
// so p = exp(0.25*dot - 0.125*sq_j - 0.125*sq_i) = exp(-dist^2/8) in (0,1]
// is the EXACT softmax numerator — no running max needed.
//
// LESSON LEDGER:
// r1: occupancy is NOT the limiter (2x occupancy, +16% time tracking +33%
//     staging rows). GEMMs are chain/staging bound.
// r2: cooperative grid.sync fusion = 383us. Dead end.
// r3: nontemporal stores neutral -> dirty-L2 probe theory dead.
// r4: BK=128 with bare __launch_bounds__(256) -> compiler SPILLED the
//     prefetch (VGPR=76, WRITE 16->138MB scratch, 95us). Chain theory
//     untested, not refuted.
// r5 (this): BK=128 + __launch_bounds__(256,2): LDS (52KB) caps us at
//     2 blk/CU anyway, so let the allocator hold ~170 VGPR of prefetch
//     in registers. Clean test of halving the serial K-chain.

__device__ __forceinline__ float b2f(ushort u) {
    union { unsigned i; float f; } x; x.i = (unsigned)u << 16; return x.f;
}
__device__ __forceinline__ ushort f2b(float f) {   // RTNE
    union { float f; unsigned i; } x; x.f = f;
    return (ushort)((x.i + 0x7FFFu + ((x.i >> 16) & 1u)) >> 16);
}

__device__ __forceinline__ void nts16(void* p, uint4 v) {
    uintx4 x; x.x = v.x; x.y = v.y; x.z = v.z; x.w = v.w;
    __builtin_nontemporal_store(x, (uintx4*)p);
}
__device__ __forceinline__ void nts16f(void* p, float4 v) {
    floatx4 x; x.x = v.x; x.y = v.y; x.z = v.z; x.w = v.w;
    __builtin_nontemporal_store(x, (floatx4*)p);
}
__device__ __forceinline__ void nts2(ushort* p, ushort v) {
    __builtin_nontemporal_store(v, p);
}

// 8 fp32 (two uint4) -> 8 bf16 via hw packed cvt (v_cvt_pk_bf16_f32, RTNE)
__device__ __forceinline__ short8 cvt8(uint4 a, uint4 b) {
    const float* f0 = (const float*)&a;
    const float* f1 = (const float*)&b;
    union { __hip_bfloat162 h; unsigned u; } c0, c1, c2, c3;
    float2 p;
    p.x = f0[0]; p.y = f0[1]; c0.h = __float22bfloat162_rn(p);
    p.x = f0[2]; p.y = f0[3]; c1.h = __float22bfloat162_rn(p);
    p.x = f1[0]; p.y = f1[1]; c2.h = __float22bfloat162_rn(p);
    p.x = f1[2]; p.y = f1[3]; c3.h = __float22bfloat162_rn(p);
    short8 s;
    unsigned* su = (unsigned*)&s;
    su[0] = c0.u; su[1] = c1.u; su[2] = c2.u; su[3] = c3.u;
    return s;
}

// ---------------------------------------------------------------------------
// MFMA GEMM core. C = A @ W_f32^T + bias_f32. 128x64 tile, BK=128 (8-iter
// chain), register prefetch held via launch_bounds(256,2), packed-cvt staging.
// OUT=0: A = x fp32 (converted during staging). Fused Q+V: blockIdx.x<16 ->
//        Q bf16 [bh,n,d]; else V^T bf16 [bh,d,n]. LDS-transposed writes.
// OUT=1: A = Oh bf16; LDS-transpose epilogue, full-line fp32 writes.
// ---------------------------------------------------------------------------
template<int OUT>
__global__ __launch_bounds__(256, 2)
void gemm_core(const void* __restrict__ Av,
               const float* __restrict__ W0, const float* __restrict__ b0,
               const float* __restrict__ W1, const float* __restrict__ b1,
               ushort* __restrict__ Qd, ushort* __restrict__ Vd,
               float* __restrict__ Fd)
{
    constexpr int AF32 = (OUT == 0) ? 1 : 0;
    __shared__ __align__(16) ushort SMEM[128 * RSK + 64 * RSK];   // 52.2 KB
    ushort* Asm = SMEM;
    ushort* Bsm = SMEM + 128 * RSK;

    const int t = threadIdx.x;
    const int w = t >> 6, lane = t & 63;
    const int lr = lane & 15, quad = lane >> 4;
    const int isV = (!OUT) && (blockIdx.x >= 16);
    const int n0 = (blockIdx.x & 15) * 64;
    const int m0 = blockIdx.y * 128;
    const float* __restrict__ W    = isV ? W1 : W0;
    const float* __restrict__ bias = isV ? b1 : b0;
    const int mw = (w >> 1) * 64, nw = (w & 1) * 32;
    // staging geometry: 16 threads cover one 128-col row (8 elems each)
    const int ar = t >> 4, ac8 = (t & 15) * 8;

    uint4 apre[AF32 ? 16 : 8], wpre[8];
    #pragma unroll
    for (int c = 0; c < 8; ++c) {
        if (AF32) {
            const float* ap = (const float*)Av + (size_t)(m0 + c * 16 + ar) * DIM + ac8;
            apre[2 * c]     = *(const uint4*)ap;
            apre[2 * c + 1] = *(const uint4*)(ap + 4);
        } else {
            apre[c] = *(const uint4*)((const ushort*)Av + (size_t)(m0 + c * 16 + ar) * DIM + ac8);
        }
    }
    #pragma unroll
    for (int c = 0; c < 4; ++c) {
        const float* wp = W + (size_t)(n0 + c * 16 + ar) * DIM + ac8;
        wpre[2 * c]     = *(const uint4*)wp;
        wpre[2 * c + 1] = *(const uint4*)(wp + 4);
    }

    floatx4 acc[4][2];
    const floatx4 fz = {0.f, 0.f, 0.f, 0.f};
    #pragma unroll
    for (int i = 0; i < 4; ++i)
        #pragma unroll
        for (int j = 0; j < 2; ++j) acc[i][j] = fz;

    for (int kt = 0; kt < NKT; ++kt) {
        #pragma unroll
        for (int c = 0; c < 8; ++c) {
            if (AF32) {
                *(short8*)&Asm[(c * 16 + ar) * RSK + ac8] = cvt8(apre[2 * c], apre[2 * c + 1]);
            } else {
                *(uint4*)&Asm[(c * 16 + ar) * RSK + ac8] = apre[c];
            }
        }
        #pragma unroll
        for (int c = 0; c < 4; ++c)
            *(short8*)&Bsm[(c * 16 + ar) * RSK + ac8] = cvt8(wpre[2 * c], wpre[2 * c + 1]);
        __syncthreads();
        if (kt < NKT - 1) {
            const int k0 = (kt + 1) * BK;
            #pragma unroll
            for (int c = 0; c < 8; ++c) {
                if (AF32) {
                    const float* ap = (const float*)Av + (size_t)(m0 + c * 16 + ar) * DIM + k0 + ac8;
                    apre[2 * c]     = *(const uint4*)ap;
                    apre[2 * c + 1] = *(const uint4*)(ap + 4);
                } else {
                    apre[c] = *(const uint4*)((const ushort*)Av + (size_t)(m0 + c * 16 + ar) * DIM + k0 + ac8);
                }
            }
            #pragma unroll
            for (int c = 0; c < 4; ++c) {
                const float* wp = W + (size_t)(n0 + c * 16 + ar) * DIM + k0 + ac8;
                wpre[2 * c]     = *(const uint4*)wp;
                wpre[2 * c + 1] = *(const uint4*)(wp + 4);
            }
        }
        // 4 k-slices of 32; fragments loaded per-slice to cap live VGPRs
        #pragma unroll
        for (int ks = 0; ks < 4; ++ks) {
            short8 af[4], bfx[2];
            #pragma unroll
            for (int tm = 0; tm < 4; ++tm)
                af[tm] = *(const short8*)&Asm[(mw + tm * 16 + lr) * RSK + ks * 32 + quad * 8];
            #pragma unroll
            for (int tn = 0; tn < 2; ++tn)
                bfx[tn] = *(const short8*)&Bsm[(nw + tn * 16 + lr) * RSK + ks * 32 + quad * 8];
            #pragma unroll
            for (int tm = 0; tm < 4; ++tm)
                #pragma unroll
                for (int tn = 0; tn < 2; ++tn)
                    acc[tm][tn] = MFMA(af[tm], bfx[tn], acc[tm][tn], 0, 0, 0);
        }
        __syncthreads();   // also protects SMEM reuse by the epilogue
    }

    // epilogue: D layout col=lane&15, row=quad*4+reg [verified m89/m91]
    if (OUT) {
        float* TF = (float*)SMEM;
        #pragma unroll
        for (int pass = 0; pass < 2; ++pass) {
            __syncthreads();
            if ((w >> 1) == pass) {
                #pragma unroll
                for (int tn = 0; tn < 2; ++tn) {
                    const float bval = bias[n0 + nw + tn * 16 + lr];
                    #pragma unroll
                    for (int tm = 0; tm < 4; ++tm)
                        #pragma unroll
                        for (int r = 0; r < 4; ++r)
                            TF[(tm * 16 + quad * 4 + r) * 68 + nw + tn * 16 + lr] =
                                acc[tm][tn][r] + bval;
                }
            }
            __syncthreads();
            #pragma unroll
            for (int it = 0; it < 4; ++it) {
                const int cid = it * 256 + t;
                const int row = cid >> 4, c4 = (cid & 15) * 4;
                nts16f(Fd + (size_t)(m0 + pass * 64 + row) * DIM + n0 + c4,
                       *(const float4*)&TF[row * 68 + c4]);
            }
        }
        return;
    }

    const int bb = m0 >> 10, ii0 = m0 & 1023;
    const int head = blockIdx.x & 15;
    const int bh = bb * HEADS + head;
    if (!isV) {
        #pragma unroll
        for (int tn = 0; tn < 2; ++tn) {
            const float bval = bias[n0 + nw + tn * 16 + lr];
            #pragma unroll
            for (int tm = 0; tm < 4; ++tm)
                #pragma unroll
                for (int r = 0; r < 4; ++r)
                    SMEM[(mw + tm * 16 + quad * 4 + r) * 80 + nw + tn * 16 + lr] =
                        f2b(acc[tm][tn][r] + bval);
        }
        __syncthreads();
        #pragma unroll
        for (int it = 0; it < 4; ++it) {
            const int cid = it * 256 + t;
            const int row = cid >> 3, col8 = (cid & 7) * 8;
            nts16(Qd + ((size_t)bh * SEQ + ii0 + row) * HD + col8,
                  *(const uint4*)&SMEM[row * 80 + col8]);
        }
    } else {
        #pragma unroll
        for (int tn = 0; tn < 2; ++tn) {
            const float bval = bias[n0 + nw + tn * 16 + lr];
            #pragma unroll
            for (int tm = 0; tm < 4; ++tm)
                #pragma unroll
                for (int r = 0; r < 4; ++r)
                    SMEM[(nw + tn * 16 + lr) * 144 + mw + tm * 16 + quad * 4 + r] =
                        f2b(acc[tm][tn][r] + bval);
        }
        __syncthreads();
        #pragma unroll
        for (int it = 0; it < 4; ++it) {
            const int cid = it * 256 + t;
            const int row = cid >> 4, col8 = (cid & 15) * 8;
            nts16(Vd + ((size_t)bh * HD + row) * SEQ + ii0 + col8,
                  *(const uint4*)&SMEM[row * 144 + col8]);
        }
    }
}

// ---------------------------------------------------------------------------
// MFMA flash L2-attention, i-tile 128 (r0-proven, unchanged).
// 512 blocks, XCD swizzle bh=id&63. Q bf16 [bh][n][64], Vt bf16 [bh][d][n].
// O bf16 [b][n][h*d].
// ---------------------------------------------------------------------------
__global__ __launch_bounds__(256)
void attn_mfma(const ushort* __restrict__ Q, const ushort* __restrict__ Vt,
               ushort* __restrict__ O)
{
    __shared__ __align__(16) ushort Ps[128 * RS];   // Q stage, then P [i][j]
    __shared__ __align__(16) ushort Ks[64 * RS];
    __shared__ __align__(16) ushort Vs[64 * RS];
    __shared__ float sqq[128], sqk[64];

    const int t = threadIdx.x;
    const int w = t >> 6, lane = t & 63;
    const int lr = lane & 15, quad = lane >> 4;
    const int id = blockIdx.x;
    const int bh = id & 63;            // 512 blocks: 8 i-blocks x 64 bh
    const int i0 = (id >> 6) * 128;
    const ushort* __restrict__ Qp = Q  + (size_t)bh * SEQ * HD;
    const ushort* __restrict__ Vp = Vt + (size_t)bh * HD * SEQ;

    const int sr = t >> 3, sc8 = (t & 7) * 8;

    #pragma unroll
    for (int it = 0; it < 4; ++it) {
        const int cid = it * 256 + t;
        const int r = cid >> 3, c8 = (cid & 7) * 8;
        *(uint4*)&Ps[r * RS + c8] = *(const uint4*)(Qp + (size_t)(i0 + r) * HD + c8);
    }
    __syncthreads();

    {
        const int qsub = quad & 1, half = quad >> 1;
        const int qr = w * 32 + qsub * 16 + lr, ch = half * 32;
        float s = 0.f;
        #pragma unroll
        for (int cc = 0; cc < 4; ++cc) {
            uint4 k = *(const uint4*)&Ps[qr * RS + ch + cc * 8];
            const ushort* u = (const ushort*)&k;
            #pragma unroll
            for (int e = 0; e < 8; ++e) { float f = b2f(u[e]); s += f * f; }
        }
        s += __shfl_xor(s, 32);
        if (half == 0) sqq[qr] = s;
    }
    __syncthreads();

    short8 qa[2][2];
    #pragma unroll
    for (int tm = 0; tm < 2; ++tm)
        #pragma unroll
        for (int ks = 0; ks < 2; ++ks)
            qa[tm][ks] = *(const short8*)&Ps[(w * 32 + tm * 16 + lr) * RS + ks * 32 + quad * 8];
    float sqi[2][4];
    #pragma unroll
    for (int tm = 0; tm < 2; ++tm)
        #pragma unroll
        for (int r = 0; r < 4; ++r)
            sqi[tm][r] = sqq[w * 32 + tm * 16 + quad * 4 + r];

    floatx4 oacc[2][4];
    const floatx4 fz = {0.f, 0.f, 0.f, 0.f};
    float lrow[2][4] = {};
    #pragma unroll
    for (int tm = 0; tm < 2; ++tm)
        #pragma unroll
        for (int td = 0; td < 4; ++td) oacc[tm][td] = fz;

    for (int jt = 0; jt < 16; ++jt) {
        const int j0 = jt * 64;
        __syncthreads();
        #pragma unroll
        for (int it = 0; it < 2; ++it) {
            const int r = it * 32 + sr;
            *(uint4*)&Ks[r * RS + sc8] = *(const uint4*)(Qp + (size_t)(j0 + r) * HD + sc8);
            *(uint4*)&Vs[r * RS + sc8] = *(const uint4*)(Vp + (size_t)r * SEQ + j0 + sc8);
        }
        __syncthreads();

        {
            const int jr = w * 16 + lr, ch = quad * 16;
            uint4 k1 = *(const uint4*)&Ks[jr * RS + ch];
            uint4 k2 = *(const uint4*)&Ks[jr * RS + ch + 8];
            const ushort* u1 = (const ushort*)&k1;
            const ushort* u2 = (const ushort*)&k2;
            float s = 0.f;
            #pragma unroll
            for (int cc = 0; cc < 8; ++cc) {
                float f1 = b2f(u1[cc]), f2 = b2f(u2[cc]);
                s += f1 * f1 + f2 * f2;
            }
            s += __shfl_xor(s, 16);
            s += __shfl_xor(s, 32);
            if (quad == 0) sqk[jr] = s;
        }
        __syncthreads();

        float sq4[4];
        #pragma unroll
        for (int tn = 0; tn < 4; ++tn) sq4[tn] = sqk[tn * 16 + lr];

        short8 kb[4][2];
        #pragma unroll
        for (int tn = 0; tn < 4; ++tn)
            #pragma unroll
            for (int ks = 0; ks < 2; ++ks)
                kb[tn][ks] = *(const short8*)&Ks[(tn * 16 + lr) * RS + ks * 32 + quad * 8];

        #pragma unroll
        for (int tm = 0; tm < 2; ++tm) {
            floatx4 sacc[4];
            #pragma unroll
            for (int tn = 0; tn < 4; ++tn) {
                floatx4 a = MFMA(qa[tm][0], kb[tn][0], fz, 0, 0, 0);
                sacc[tn]  = MFMA(qa[tm][1], kb[tn][1], a, 0, 0, 0);
            }
            float sc[4][4];
            #pragma unroll
            for (int tn = 0; tn < 4; ++tn) {
                const float msq = -0.125f * sq4[tn];
                #pragma unroll
                for (int r = 0; r < 4; ++r)
                    sc[tn][r] = __expf(0.25f * sacc[tn][r] + msq - 0.125f * sqi[tm][r]);
            }
            #pragma unroll
            for (int r = 0; r < 4; ++r)
                lrow[tm][r] += sc[0][r] + sc[1][r] + sc[2][r] + sc[3][r];
            #pragma unroll
            for (int tp = 0; tp < 2; ++tp)
                #pragma unroll
                for (int r = 0; r < 4; ++r) {
                    float2 fp; fp.x = sc[2 * tp][r]; fp.y = sc[2 * tp + 1][r];
                    union { __hip_bfloat162 h; unsigned u; } cv;
                    cv.h = __float22bfloat162_rn(fp);
                    const int rowb = (w * 32 + tm * 16 + quad * 4 + r) * RS + lr;
                    Ps[rowb + (2 * tp) * 16]     = (ushort)(cv.u & 0xffffu);
                    Ps[rowb + (2 * tp + 1) * 16] = (ushort)(cv.u >> 16);
                }
        }
        __syncthreads();   // P stores visible before PV fragment reads

        short8 pa[2][2], vb[4][2];
        #pragma unroll
        for (int tm = 0; tm < 2; ++tm)
            #pragma unroll
            for (int ks = 0; ks < 2; ++ks)
                pa[tm][ks] = *(const short8*)&Ps[(w * 32 + tm * 16 + lr) * RS + ks * 32 + quad * 8];
        #pragma unroll
        for (int td = 0; td < 4; ++td)
            #pragma unroll
            for (int ks = 0; ks < 2; ++ks)
                vb[td][ks] = *(const short8*)&Vs[(td * 16 + lr) * RS + ks * 32 + quad * 8];
        #pragma unroll
        for (int tm = 0; tm < 2; ++tm)
            #pragma unroll
            for (int td = 0; td < 4; ++td) {
                oacc[tm][td] = MFMA(pa[tm][0], vb[td][0], oacc[tm][td], 0, 0, 0);
                oacc[tm][td] = MFMA(pa[tm][1], vb[td][1], oacc[tm][td], 0, 0, 0);
            }
    }

    const int bb = bh >> 4, head = bh & 15;
    #pragma unroll
    for (int tm = 0; tm < 2; ++tm)
        #pragma unroll
        for (int r = 0; r < 4; ++r) {
            float l = lrow[tm][r];
            l += __shfl_xor(l, 1);
            l += __shfl_xor(l, 2);
            l += __shfl_xor(l, 4);
            l += __shfl_xor(l, 8);
            const float inv = 1.f / l;
            const int row = i0 + w * 32 + tm * 16 + quad * 4 + r;
            #pragma unroll
            for (int td = 0; td < 4; ++td) {
                nts2(O + (size_t)(bb * SEQ + row) * DIM + head * HD + td * 16 + lr,
                     f2b(oacc[tm][td][r] * inv));
            }
        }
}

extern "C" void kernel_launch(void* const* d_in, const int* in_sizes, int n_in,
                              void* d_out, int out_size, void* d_ws, size_t ws_size,
                              hipStream_t stream)
{
    const float* x  = (const float*)d_in[0];
    const float* Wq = (const float*)d_in[1];
    const float* bq = (const float*)d_in[2];
    const float* Wv = (const float*)d_in[3];
    const float* bv = (const float*)d_in[4];
    const float* Wo = (const float*)d_in[5];
    const float* bo = (const float*)d_in[6];

    // d_ws (proven 24 MB): Qh 8MB | Vt 8MB | Oh 8MB
    ushort* Qh = (ushort*)d_ws;
    ushort* Vt = Qh + (size_t)BATCH * HEADS * SEQ * HD;
    ushort* Oh = Vt + (size_t)BATCH * HEADS * SEQ * HD;

    gemm_core<0><<<dim3(32, 32), 256, 0, stream>>>(x, Wq, bq, Wv, bv, Qh, Vt, nullptr);
    attn_mfma<<<512, 256, 0, stream>>>(Qh, Vt, Oh);
    gemm_core<1><<<dim3(16, 32), 256, 0, stream>>>(Oh, Wo, bo, nullptr, nullptr,
                                                   nullptr, nullptr, (float*)d_out);
}

// Round 6
// 187.278 us; speedup vs baseline: 1.3510x; 1.1726x over previous
//
#include <hip/hip_runtime.h>
#include <hip/hip_bf16.h>

typedef __hip_bfloat16 bf16;
typedef short short8 __attribute__((ext_vector_type(8)));
typedef float floatx4 __attribute__((ext_vector_type(4)));
typedef unsigned uintx4 __attribute__((ext_vector_type(4)));
typedef unsigned short ushort;

#define MFMA __builtin_amdgcn_mfma_f32_16x16x32_bf16

#define BATCH 4
#define SEQ   1024
#define DIM   1024
#define HEADS 16
#define HD    64
#define RS    72    // attn + GEMM-B LDS row stride in shorts (64 + 8 pad)

// scores = -(sq_i - 2 q.k + sq_j)*0.125. Analytic max = self-score (dist=0),
// so p = exp(0.25*dot - 0.125*sq_j - 0.125*sq_i) = exp(-dist^2/8) in (0,1]
// is the EXACT softmax numerator — no running max needed.
//
// LESSON LEDGER:
// r1: occupancy is NOT the limiter (2x occupancy, +16% time tracking +33%
//     staging rows). GEMMs are chain/staging bound.
// r2: cooperative grid.sync fusion = 383us. Dead end.
// r3: nontemporal stores neutral -> dirty-L2 probe theory dead; producer->
//     consumer scratch reads (attn reads Qh/Vt) are fine.
// r4: BK=128, bare launch_bounds: prefetch spilled (VGPR=76, WRITE 138MB).
// r5: launch_bounds(256,2) did NOT fix it (VGPR=88, WRITE 97MB) — hipcc
//     refuses to hold big prefetch arrays across barrier+MFMA regions.
//     BK=128 register-prefetch lane is DEAD.
// r6 (this): the guide's proven +69% step (m93->m97): A-staging via
//     __builtin_amdgcn_global_load_lds(16B), double-buffered A (linear LDS,
//     required by gload_lds), B stays reg+cvt8 (padded LDS). x pre-converted
//     to bf16 once (conv_x) so A is loadable directly. Workspace still 24MB
//     (Oh aliases xb).

__device__ __forceinline__ float b2f(ushort u) {
    union { unsigned i; float f; } x; x.i = (unsigned)u << 16; return x.f;
}
__device__ __forceinline__ ushort f2b(float f) {   // RTNE
    union { float f; unsigned i; } x; x.f = f;
    return (ushort)((x.i + 0x7FFFu + ((x.i >> 16) & 1u)) >> 16);
}

__device__ __forceinline__ void nts16(void* p, uint4 v) {
    uintx4 x; x.x = v.x; x.y = v.y; x.z = v.z; x.w = v.w;
    __builtin_nontemporal_store(x, (uintx4*)p);
}
__device__ __forceinline__ void nts16f(void* p, float4 v) {
    floatx4 x; x.x = v.x; x.y = v.y; x.z = v.z; x.w = v.w;
    __builtin_nontemporal_store(x, (floatx4*)p);
}
__device__ __forceinline__ void nts2(ushort* p, ushort v) {
    __builtin_nontemporal_store(v, p);
}

// async global->LDS, 16B per lane; LDS dest = wave-uniform base + lane*16
__device__ __forceinline__ void gload16(const ushort* gp, ushort* lp) {
    __builtin_amdgcn_global_load_lds(
        (const __attribute__((address_space(1))) unsigned*)gp,
        (__attribute__((address_space(3))) unsigned*)lp, 16, 0, 0);
}

// 8 fp32 (two uint4) -> 8 bf16 via hw packed cvt (v_cvt_pk_bf16_f32, RTNE)
__device__ __forceinline__ short8 cvt8(uint4 a, uint4 b) {
    const float* f0 = (const float*)&a;
    const float* f1 = (const float*)&b;
    union { __hip_bfloat162 h; unsigned u; } c0, c1, c2, c3;
    float2 p;
    p.x = f0[0]; p.y = f0[1]; c0.h = __float22bfloat162_rn(p);
    p.x = f0[2]; p.y = f0[3]; c1.h = __float22bfloat162_rn(p);
    p.x = f1[0]; p.y = f1[1]; c2.h = __float22bfloat162_rn(p);
    p.x = f1[2]; p.y = f1[3]; c3.h = __float22bfloat162_rn(p);
    short8 s;
    unsigned* su = (unsigned*)&s;
    su[0] = c0.u; su[1] = c1.u; su[2] = c2.u; su[3] = c3.u;
    return s;
}

// ---------------------------------------------------------------------------
// conv_x: x fp32 [4096][1024] -> xb bf16 (RTNE, identical bits to in-staging
// conversion). 2048 blocks x 256 thr, 8 floats/thread, coalesced.
// ---------------------------------------------------------------------------
__global__ __launch_bounds__(256)
void conv_x(const float* __restrict__ x, ushort* __restrict__ xb)
{
    const size_t g = (size_t)blockIdx.x * 256 + threadIdx.x;
    const uint4* xv = (const uint4*)x;
    uint4 a = xv[g * 2], b = xv[g * 2 + 1];
    short8 s = cvt8(a, b);
    nts16(xb + g * 8, *(uint4*)&s);
}

// ---------------------------------------------------------------------------
// MFMA GEMM core. C = A_bf16 @ W_f32^T + bias. 128x64 tile, BK=64.
// A: global_load_lds 16B, double-buffered LINEAR LDS [128][64] (gload_lds
//    requires contiguous dest). Issued at compute-start of the previous
//    step -> latency hidden under 16 MFMA + frag reads.
// B: fp32 W, register prefetch + cvt8, padded LDS [64][72].
// OUT=0: A = xb. Fused Q+V: blockIdx.x<16 -> Q bf16 [bh,n,d]; else V^T
//        bf16 [bh,d,n]. OUT=1: A = Oh; fp32 epilogue via LDS transpose.
// ---------------------------------------------------------------------------
template<int OUT>
__global__ __launch_bounds__(256, 3)
void gemm_core(const ushort* __restrict__ Ab,
               const float* __restrict__ W0, const float* __restrict__ b0,
               const float* __restrict__ W1, const float* __restrict__ b1,
               ushort* __restrict__ Qd, ushort* __restrict__ Vd,
               float* __restrict__ Fd)
{
    __shared__ __align__(16) ushort SMEM[2 * 128 * 64 + 64 * RS];   // 41 KB
    ushort* A0  = SMEM;                 // 8192 shorts
    ushort* A1  = SMEM + 8192;
    ushort* Bsm = SMEM + 16384;         // 64 x 72

    const int t = threadIdx.x;
    const int w = t >> 6, lane = t & 63;
    const int lr = lane & 15, quad = lane >> 4;
    const int isV = (!OUT) && (blockIdx.x >= 16);
    const int n0 = (blockIdx.x & 15) * 64;
    const int m0 = blockIdx.y * 128;
    const float* __restrict__ W    = isV ? W1 : W0;
    const float* __restrict__ bias = isV ? b1 : b0;
    const int mw = (w >> 1) * 64, nw = (w & 1) * 32;
    const int ar = t >> 3, ac8 = (t & 7) * 8;

    // A-stage geometry: wave w covers LDS shorts [(w*4+i)*512 .. +512),
    // lane adds l*8. row = (w*4+i)*8 + (l>>3), col = (l&7)*8.
    const int arow = (lane >> 3), acol = (lane & 7) * 8;

    // B prefetch (64x64 fp32 = 16KB; 16 floats/thread)
    uint4 wpre[4];
    #pragma unroll
    for (int c = 0; c < 2; ++c) {
        const float* wp = W + (size_t)(n0 + c * 32 + ar) * DIM + ac8;
        wpre[2 * c]     = *(const uint4*)wp;
        wpre[2 * c + 1] = *(const uint4*)(wp + 4);
    }
    // A stage for kt=0 into A0
    {
        #pragma unroll
        for (int i = 0; i < 4; ++i) {
            const int chunk = w * 4 + i;
            const int row = chunk * 8 + arow;
            gload16(Ab + (size_t)(m0 + row) * DIM + acol,
                    A0 + chunk * 512);
        }
    }

    floatx4 acc[4][2];
    const floatx4 fz = {0.f, 0.f, 0.f, 0.f};
    #pragma unroll
    for (int i = 0; i < 4; ++i)
        #pragma unroll
        for (int j = 0; j < 2; ++j) acc[i][j] = fz;

    ushort* Acur = A0;
    ushort* Anxt = A1;

    for (int kt = 0; kt < 16; ++kt) {
        // B(kt) regs -> LDS (Bsm free: previous compute barrier passed)
        #pragma unroll
        for (int c = 0; c < 2; ++c)
            *(short8*)&Bsm[(c * 32 + ar) * RS + ac8] = cvt8(wpre[2 * c], wpre[2 * c + 1]);
        __syncthreads();   // drains A(kt) gloads; B(kt) visible
        if (kt < 15) {
            const int k0 = (kt + 1) * 64;
            // async A(kt+1) into the buffer not being read; latency rides
            // under this step's MFMAs, drained by the end-of-step barrier.
            #pragma unroll
            for (int i = 0; i < 4; ++i) {
                const int chunk = w * 4 + i;
                const int row = chunk * 8 + arow;
                gload16(Ab + (size_t)(m0 + row) * DIM + k0 + acol,
                        Anxt + chunk * 512);
            }
            // B(kt+1) global fp32 -> regs, consumed next iteration
            #pragma unroll
            for (int c = 0; c < 2; ++c) {
                const float* wp = W + (size_t)(n0 + c * 32 + ar) * DIM + k0 + ac8;
                wpre[2 * c]     = *(const uint4*)wp;
                wpre[2 * c + 1] = *(const uint4*)(wp + 4);
            }
        }
        #pragma unroll
        for (int ks = 0; ks < 2; ++ks) {
            short8 af[4], bfx[2];
            #pragma unroll
            for (int tm = 0; tm < 4; ++tm)
                af[tm] = *(const short8*)&Acur[(mw + tm * 16 + lr) * 64 + ks * 32 + quad * 8];
            #pragma unroll
            for (int tn = 0; tn < 2; ++tn)
                bfx[tn] = *(const short8*)&Bsm[(nw + tn * 16 + lr) * RS + ks * 32 + quad * 8];
            #pragma unroll
            for (int tm = 0; tm < 4; ++tm)
                #pragma unroll
                for (int tn = 0; tn < 2; ++tn)
                    acc[tm][tn] = MFMA(af[tm], bfx[tn], acc[tm][tn], 0, 0, 0);
        }
        __syncthreads();   // all reads done; also drains A(kt+1) (covered)
        ushort* tmp = Acur; Acur = Anxt; Anxt = tmp;
    }

    // epilogue: D layout col=lane&15, row=quad*4+reg [verified m89/m91]
    if (OUT) {
        float* TF = (float*)SMEM;
        #pragma unroll
        for (int pass = 0; pass < 2; ++pass) {
            __syncthreads();
            if ((w >> 1) == pass) {
                #pragma unroll
                for (int tn = 0; tn < 2; ++tn) {
                    const float bval = bias[n0 + nw + tn * 16 + lr];
                    #pragma unroll
                    for (int tm = 0; tm < 4; ++tm)
                        #pragma unroll
                        for (int r = 0; r < 4; ++r)
                            TF[(tm * 16 + quad * 4 + r) * 68 + nw + tn * 16 + lr] =
                                acc[tm][tn][r] + bval;
                }
            }
            __syncthreads();
            #pragma unroll
            for (int it = 0; it < 4; ++it) {
                const int cid = it * 256 + t;
                const int row = cid >> 4, c4 = (cid & 15) * 4;
                nts16f(Fd + (size_t)(m0 + pass * 64 + row) * DIM + n0 + c4,
                       *(const float4*)&TF[row * 68 + c4]);
            }
        }
        return;
    }

    const int bb = m0 >> 10, ii0 = m0 & 1023;
    const int head = blockIdx.x & 15;
    const int bh = bb * HEADS + head;
    if (!isV) {
        #pragma unroll
        for (int tn = 0; tn < 2; ++tn) {
            const float bval = bias[n0 + nw + tn * 16 + lr];
            #pragma unroll
            for (int tm = 0; tm < 4; ++tm)
                #pragma unroll
                for (int r = 0; r < 4; ++r)
                    SMEM[(mw + tm * 16 + quad * 4 + r) * 80 + nw + tn * 16 + lr] =
                        f2b(acc[tm][tn][r] + bval);
        }
        __syncthreads();
        #pragma unroll
        for (int it = 0; it < 4; ++it) {
            const int cid = it * 256 + t;
            const int row = cid >> 3, col8 = (cid & 7) * 8;
            nts16(Qd + ((size_t)bh * SEQ + ii0 + row) * HD + col8,
                  *(const uint4*)&SMEM[row * 80 + col8]);
        }
    } else {
        #pragma unroll
        for (int tn = 0; tn < 2; ++tn) {
            const float bval = bias[n0 + nw + tn * 16 + lr];
            #pragma unroll
            for (int tm = 0; tm < 4; ++tm)
                #pragma unroll
                for (int r = 0; r < 4; ++r)
                    SMEM[(nw + tn * 16 + lr) * 144 + mw + tm * 16 + quad * 4 + r] =
                        f2b(acc[tm][tn][r] + bval);
        }
        __syncthreads();
        #pragma unroll
        for (int it = 0; it < 4; ++it) {
            const int cid = it * 256 + t;
            const int row = cid >> 4, col8 = (cid & 15) * 8;
            nts16(Vd + ((size_t)bh * HD + row) * SEQ + ii0 + col8,
                  *(const uint4*)&SMEM[row * 144 + col8]);
        }
    }
}

// ---------------------------------------------------------------------------
// MFMA flash L2-attention, i-tile 128 (r0-proven, unchanged).
// 512 blocks, XCD swizzle bh=id&63. Q bf16 [bh][n][64], Vt bf16 [bh][d][n].
// O bf16 [b][n][h*d].
// ---------------------------------------------------------------------------
__global__ __launch_bounds__(256)
void attn_mfma(const ushort* __restrict__ Q, const ushort* __restrict__ Vt,
               ushort* __restrict__ O)
{
    __shared__ __align__(16) ushort Ps[128 * RS];   // Q stage, then P [i][j]
    __shared__ __align__(16) ushort Ks[64 * RS];
    __shared__ __align__(16) ushort Vs[64 * RS];
    __shared__ float sqq[128], sqk[64];

    const int t = threadIdx.x;
    const int w = t >> 6, lane = t & 63;
    const int lr = lane & 15, quad = lane >> 4;
    const int id = blockIdx.x;
    const int bh = id & 63;            // 512 blocks: 8 i-blocks x 64 bh
    const int i0 = (id >> 6) * 128;
    const ushort* __restrict__ Qp = Q  + (size_t)bh * SEQ * HD;
    const ushort* __restrict__ Vp = Vt + (size_t)bh * HD * SEQ;

    const int sr = t >> 3, sc8 = (t & 7) * 8;

    #pragma unroll
    for (int it = 0; it < 4; ++it) {
        const int cid = it * 256 + t;
        const int r = cid >> 3, c8 = (cid & 7) * 8;
        *(uint4*)&Ps[r * RS + c8] = *(const uint4*)(Qp + (size_t)(i0 + r) * HD + c8);
    }
    __syncthreads();

    {
        const int qsub = quad & 1, half = quad >> 1;
        const int qr = w * 32 + qsub * 16 + lr, ch = half * 32;
        float s = 0.f;
        #pragma unroll
        for (int cc = 0; cc < 4; ++cc) {
            uint4 k = *(const uint4*)&Ps[qr * RS + ch + cc * 8];
            const ushort* u = (const ushort*)&k;
            #pragma unroll
            for (int e = 0; e < 8; ++e) { float f = b2f(u[e]); s += f * f; }
        }
        s += __shfl_xor(s, 32);
        if (half == 0) sqq[qr] = s;
    }
    __syncthreads();

    short8 qa[2][2];
    #pragma unroll
    for (int tm = 0; tm < 2; ++tm)
        #pragma unroll
        for (int ks = 0; ks < 2; ++ks)
            qa[tm][ks] = *(const short8*)&Ps[(w * 32 + tm * 16 + lr) * RS + ks * 32 + quad * 8];
    float sqi[2][4];
    #pragma unroll
    for (int tm = 0; tm < 2; ++tm)
        #pragma unroll
        for (int r = 0; r < 4; ++r)
            sqi[tm][r] = sqq[w * 32 + tm * 16 + quad * 4 + r];

    floatx4 oacc[2][4];
    const floatx4 fz = {0.f, 0.f, 0.f, 0.f};
    float lrow[2][4] = {};
    #pragma unroll
    for (int tm = 0; tm < 2; ++tm)
        #pragma unroll
        for (int td = 0; td < 4; ++td) oacc[tm][td] = fz;

    for (int jt = 0; jt < 16; ++jt) {
        const int j0 = jt * 64;
        __syncthreads();
        #pragma unroll
        for (int it = 0; it < 2; ++it) {
            const int r = it * 32 + sr;
            *(uint4*)&Ks[r * RS + sc8] = *(const uint4*)(Qp + (size_t)(j0 + r) * HD + sc8);
            *(uint4*)&Vs[r * RS + sc8] = *(const uint4*)(Vp + (size_t)r * SEQ + j0 + sc8);
        }
        __syncthreads();

        {
            const int jr = w * 16 + lr, ch = quad * 16;
            uint4 k1 = *(const uint4*)&Ks[jr * RS + ch];
            uint4 k2 = *(const uint4*)&Ks[jr * RS + ch + 8];
            const ushort* u1 = (const ushort*)&k1;
            const ushort* u2 = (const ushort*)&k2;
            float s = 0.f;
            #pragma unroll
            for (int cc = 0; cc < 8; ++cc) {
                float f1 = b2f(u1[cc]), f2 = b2f(u2[cc]);
                s += f1 * f1 + f2 * f2;
            }
            s += __shfl_xor(s, 16);
            s += __shfl_xor(s, 32);
            if (quad == 0) sqk[jr] = s;
        }
        __syncthreads();

        float sq4[4];
        #pragma unroll
        for (int tn = 0; tn < 4; ++tn) sq4[tn] = sqk[tn * 16 + lr];

        short8 kb[4][2];
        #pragma unroll
        for (int tn = 0; tn < 4; ++tn)
            #pragma unroll
            for (int ks = 0; ks < 2; ++ks)
                kb[tn][ks] = *(const short8*)&Ks[(tn * 16 + lr) * RS + ks * 32 + quad * 8];

        #pragma unroll
        for (int tm = 0; tm < 2; ++tm) {
            floatx4 sacc[4];
            #pragma unroll
            for (int tn = 0; tn < 4; ++tn) {
                floatx4 a = MFMA(qa[tm][0], kb[tn][0], fz, 0, 0, 0);
                sacc[tn]  = MFMA(qa[tm][1], kb[tn][1], a, 0, 0, 0);
            }
            float sc[4][4];
            #pragma unroll
            for (int tn = 0; tn < 4; ++tn) {
                const float msq = -0.125f * sq4[tn];
                #pragma unroll
                for (int r = 0; r < 4; ++r)
                    sc[tn][r] = __expf(0.25f * sacc[tn][r] + msq - 0.125f * sqi[tm][r]);
            }
            #pragma unroll
            for (int r = 0; r < 4; ++r)
                lrow[tm][r] += sc[0][r] + sc[1][r] + sc[2][r] + sc[3][r];
            #pragma unroll
            for (int tp = 0; tp < 2; ++tp)
                #pragma unroll
                for (int r = 0; r < 4; ++r) {
                    float2 fp; fp.x = sc[2 * tp][r]; fp.y = sc[2 * tp + 1][r];
                    union { __hip_bfloat162 h; unsigned u; } cv;
                    cv.h = __float22bfloat162_rn(fp);
                    const int rowb = (w * 32 + tm * 16 + quad * 4 + r) * RS + lr;
                    Ps[rowb + (2 * tp) * 16]     = (ushort)(cv.u & 0xffffu);
                    Ps[rowb + (2 * tp + 1) * 16] = (ushort)(cv.u >> 16);
                }
        }
        __syncthreads();   // P stores visible before PV fragment reads

        short8 pa[2][2], vb[4][2];
        #pragma unroll
        for (int tm = 0; tm < 2; ++tm)
            #pragma unroll
            for (int ks = 0; ks < 2; ++ks)
                pa[tm][ks] = *(const short8*)&Ps[(w * 32 + tm * 16 + lr) * RS + ks * 32 + quad * 8];
        #pragma unroll
        for (int td = 0; td < 4; ++td)
            #pragma unroll
            for (int ks = 0; ks < 2; ++ks)
                vb[td][ks] = *(const short8*)&Vs[(td * 16 + lr) * RS + ks * 32 + quad * 8];
        #pragma unroll
        for (int tm = 0; tm < 2; ++tm)
            #pragma unroll
            for (int td = 0; td < 4; ++td) {
                oacc[tm][td] = MFMA(pa[tm][0], vb[td][0], oacc[tm][td], 0, 0, 0);
                oacc[tm][td] = MFMA(pa[tm][1], vb[td][1], oacc[tm][td], 0, 0, 0);
            }
    }

    const int bb = bh >> 4, head = bh & 15;
    #pragma unroll
    for (int tm = 0; tm < 2; ++tm)
        #pragma unroll
        for (int r = 0; r < 4; ++r) {
            float l = lrow[tm][r];
            l += __shfl_xor(l, 1);
            l += __shfl_xor(l, 2);
            l += __shfl_xor(l, 4);
            l += __shfl_xor(l, 8);
            const float inv = 1.f / l;
            const int row = i0 + w * 32 + tm * 16 + quad * 4 + r;
            #pragma unroll
            for (int td = 0; td < 4; ++td) {
                nts2(O + (size_t)(bb * SEQ + row) * DIM + head * HD + td * 16 + lr,
                     f2b(oacc[tm][td][r] * inv));
            }
        }
}

extern "C" void kernel_launch(void* const* d_in, const int* in_sizes, int n_in,
                              void* d_out, int out_size, void* d_ws, size_t ws_size,
                              hipStream_t stream)
{
    const float* x  = (const float*)d_in[0];
    const float* Wq = (const float*)d_in[1];
    const float* bq = (const float*)d_in[2];
    const float* Wv = (const float*)d_in[3];
    const float* bv = (const float*)d_in[4];
    const float* Wo = (const float*)d_in[5];
    const float* bo = (const float*)d_in[6];

    // d_ws (proven 24 MB): Qh 8MB | Vt 8MB | R 8MB (xb for QV, then Oh)
    ushort* Qh = (ushort*)d_ws;
    ushort* Vt = Qh + (size_t)BATCH * HEADS * SEQ * HD;
    ushort* R  = Vt + (size_t)BATCH * HEADS * SEQ * HD;

    conv_x<<<2048, 256, 0, stream>>>(x, R);
    gemm_core<0><<<dim3(32, 32), 256, 0, stream>>>(R, Wq, bq, Wv, bv, Qh, Vt, nullptr);
    attn_mfma<<<512, 256, 0, stream>>>(Qh, Vt, R);   // Oh overwrites xb (dead)
    gemm_core<1><<<dim3(16, 32), 256, 0, stream>>>(R, Wo, bo, nullptr, nullptr,
                                                   nullptr, nullptr, (float*)d_out);
}

// Round 7
// 183.752 us; speedup vs baseline: 1.3769x; 1.0192x over previous
//
#include <hip/hip_runtime.h>
#include <hip/hip_bf16.h>

typedef __hip_bfloat16 bf16;
typedef short short8 __attribute__((ext_vector_type(8)));
typedef float floatx4 __attribute__((ext_vector_type(4)));
typedef unsigned uintx4 __attribute__((ext_vector_type(4)));
typedef unsigned short ushort;

#define MFMA __builtin_amdgcn_mfma_f32_16x16x32_bf16

#define BATCH 4
#define SEQ   1024
#define DIM   1024
#define HEADS 16
#define HD    64
#define RS    72    // attn + GEMM-B LDS row stride in shorts (64 + 8 pad)

// scores = -(sq_i - 2 q.k + sq_j)*0.125. Analytic max = self-score (dist=0),
// so p = exp(0.25*dot - 0.125*sq_j - 0.125*sq_i) = exp(-dist^2/8) in (0,1]
// is the EXACT softmax numerator — no running max needed.
//
// LESSON LEDGER:
// r1: occupancy is NOT the limiter. GEMMs are chain/staging bound.
// r2: cooperative grid.sync fusion = 383us. Dead end.
// r3: nontemporal stores neutral -> dirty-L2 probe theory dead; producer->
//     consumer scratch reads are fine.
// r4/r5: BK=128 register prefetch spills regardless of launch_bounds —
//     hipcc won't hold big arrays across barrier+MFMA. Lane DEAD.
// r6: global_load_lds A-staging: 203->187us (gemm<0> 54->47.5, FETCH 73->40MB,
//     VALU 34->16%). BUT linear [128][64] LDS -> 16-way bank conflict on
//     A-frag reads (SQ_LDS_BANK_CONFLICT 3.6M->7.8M ~= 12.6us/CU serial).
// r7 (this): T2 both-sides swizzle (rule #21): pre-swizzle the GLOBAL source
//     chunk (lane&7)^(row&7), read at chunk^(row&7); LDS stays linear.
//     16-way -> 2-way (free).

__device__ __forceinline__ float b2f(ushort u) {
    union { unsigned i; float f; } x; x.i = (unsigned)u << 16; return x.f;
}
__device__ __forceinline__ ushort f2b(float f) {   // RTNE
    union { float f; unsigned i; } x; x.f = f;
    return (ushort)((x.i + 0x7FFFu + ((x.i >> 16) & 1u)) >> 16);
}

__device__ __forceinline__ void nts16(void* p, uint4 v) {
    uintx4 x; x.x = v.x; x.y = v.y; x.z = v.z; x.w = v.w;
    __builtin_nontemporal_store(x, (uintx4*)p);
}
__device__ __forceinline__ void nts16f(void* p, float4 v) {
    floatx4 x; x.x = v.x; x.y = v.y; x.z = v.z; x.w = v.w;
    __builtin_nontemporal_store(x, (floatx4*)p);
}
__device__ __forceinline__ void nts2(ushort* p, ushort v) {
    __builtin_nontemporal_store(v, p);
}

// async global->LDS, 16B per lane; LDS dest = wave-uniform base + lane*16
__device__ __forceinline__ void gload16(const ushort* gp, ushort* lp) {
    __builtin_amdgcn_global_load_lds(
        (const __attribute__((address_space(1))) unsigned*)gp,
        (__attribute__((address_space(3))) unsigned*)lp, 16, 0, 0);
}

// 8 fp32 (two uint4) -> 8 bf16 via hw packed cvt (v_cvt_pk_bf16_f32, RTNE)
__device__ __forceinline__ short8 cvt8(uint4 a, uint4 b) {
    const float* f0 = (const float*)&a;
    const float* f1 = (const float*)&b;
    union { __hip_bfloat162 h; unsigned u; } c0, c1, c2, c3;
    float2 p;
    p.x = f0[0]; p.y = f0[1]; c0.h = __float22bfloat162_rn(p);
    p.x = f0[2]; p.y = f0[3]; c1.h = __float22bfloat162_rn(p);
    p.x = f1[0]; p.y = f1[1]; c2.h = __float22bfloat162_rn(p);
    p.x = f1[2]; p.y = f1[3]; c3.h = __float22bfloat162_rn(p);
    short8 s;
    unsigned* su = (unsigned*)&s;
    su[0] = c0.u; su[1] = c1.u; su[2] = c2.u; su[3] = c3.u;
    return s;
}

// ---------------------------------------------------------------------------
// conv_x: x fp32 [4096][1024] -> xb bf16 (RTNE, identical bits to in-staging
// conversion). 2048 blocks x 256 thr, 8 floats/thread, coalesced.
// ---------------------------------------------------------------------------
__global__ __launch_bounds__(256)
void conv_x(const float* __restrict__ x, ushort* __restrict__ xb)
{
    const size_t g = (size_t)blockIdx.x * 256 + threadIdx.x;
    const uint4* xv = (const uint4*)x;
    uint4 a = xv[g * 2], b = xv[g * 2 + 1];
    short8 s = cvt8(a, b);
    nts16(xb + g * 8, *(uint4*)&s);
}

// ---------------------------------------------------------------------------
// MFMA GEMM core. C = A_bf16 @ W_f32^T + bias. 128x64 tile, BK=64.
// A: global_load_lds 16B, double-buffered LINEAR LDS [128][64], XOR-swizzled
//    via pre-swizzled GLOBAL source (rule #21): LDS(row, c) = G(row, c^(row&7))
//    in 16B chunks; read at chunk^(row&7). 16-way conflict -> 2-way (free).
// B: fp32 W, register prefetch + cvt8, padded LDS [64][72] (2-way, free).
// OUT=0: A = xb. Fused Q+V: blockIdx.x<16 -> Q bf16 [bh,n,d]; else V^T
//        bf16 [bh,d,n]. OUT=1: A = Oh; fp32 epilogue via LDS transpose.
// ---------------------------------------------------------------------------
template<int OUT>
__global__ __launch_bounds__(256, 3)
void gemm_core(const ushort* __restrict__ Ab,
               const float* __restrict__ W0, const float* __restrict__ b0,
               const float* __restrict__ W1, const float* __restrict__ b1,
               ushort* __restrict__ Qd, ushort* __restrict__ Vd,
               float* __restrict__ Fd)
{
    __shared__ __align__(16) ushort SMEM[2 * 128 * 64 + 64 * RS];   // 41 KB
    ushort* A0  = SMEM;                 // 8192 shorts
    ushort* A1  = SMEM + 8192;
    ushort* Bsm = SMEM + 16384;         // 64 x 72

    const int t = threadIdx.x;
    const int w = t >> 6, lane = t & 63;
    const int lr = lane & 15, quad = lane >> 4;
    const int isV = (!OUT) && (blockIdx.x >= 16);
    const int n0 = (blockIdx.x & 15) * 64;
    const int m0 = blockIdx.y * 128;
    const float* __restrict__ W    = isV ? W1 : W0;
    const float* __restrict__ bias = isV ? b1 : b0;
    const int mw = (w >> 1) * 64, nw = (w & 1) * 32;
    const int ar = t >> 3, ac8 = (t & 7) * 8;

    // A-stage geometry: wave w covers LDS shorts [(w*4+i)*512 .. +512),
    // lane writes LDS chunk (lane&7) of row chunk*8+(lane>>3); the GLOBAL
    // source chunk is XOR-swizzled by row&7 = lane>>3 (T2, rule #21).
    const int arow = (lane >> 3);
    const int acS  = ((lane & 7) ^ arow) * 8;   // swizzled source col (shorts)

    // B prefetch (64x64 fp32 = 16KB; 16 floats/thread)
    uint4 wpre[4];
    #pragma unroll
    for (int c = 0; c < 2; ++c) {
        const float* wp = W + (size_t)(n0 + c * 32 + ar) * DIM + ac8;
        wpre[2 * c]     = *(const uint4*)wp;
        wpre[2 * c + 1] = *(const uint4*)(wp + 4);
    }
    // A stage for kt=0 into A0
    {
        #pragma unroll
        for (int i = 0; i < 4; ++i) {
            const int chunk = w * 4 + i;
            const int row = chunk * 8 + arow;
            gload16(Ab + (size_t)(m0 + row) * DIM + acS,
                    A0 + chunk * 512);
        }
    }

    floatx4 acc[4][2];
    const floatx4 fz = {0.f, 0.f, 0.f, 0.f};
    #pragma unroll
    for (int i = 0; i < 4; ++i)
        #pragma unroll
        for (int j = 0; j < 2; ++j) acc[i][j] = fz;

    ushort* Acur = A0;
    ushort* Anxt = A1;

    for (int kt = 0; kt < 16; ++kt) {
        // B(kt) regs -> LDS (Bsm free: previous compute barrier passed)
        #pragma unroll
        for (int c = 0; c < 2; ++c)
            *(short8*)&Bsm[(c * 32 + ar) * RS + ac8] = cvt8(wpre[2 * c], wpre[2 * c + 1]);
        __syncthreads();   // drains A(kt) gloads; B(kt) visible
        if (kt < 15) {
            const int k0 = (kt + 1) * 64;
            // async A(kt+1) into the buffer not being read; latency rides
            // under this step's MFMAs, drained by the end-of-step barrier.
            #pragma unroll
            for (int i = 0; i < 4; ++i) {
                const int chunk = w * 4 + i;
                const int row = chunk * 8 + arow;
                gload16(Ab + (size_t)(m0 + row) * DIM + k0 + acS,
                        Anxt + chunk * 512);
            }
            // B(kt+1) global fp32 -> regs, consumed next iteration
            #pragma unroll
            for (int c = 0; c < 2; ++c) {
                const float* wp = W + (size_t)(n0 + c * 32 + ar) * DIM + k0 + ac8;
                wpre[2 * c]     = *(const uint4*)wp;
                wpre[2 * c + 1] = *(const uint4*)(wp + 4);
            }
        }
        #pragma unroll
        for (int ks = 0; ks < 2; ++ks) {
            short8 af[4], bfx[2];
            #pragma unroll
            for (int tm = 0; tm < 4; ++tm) {
                const int rowa = mw + tm * 16 + lr;          // rowa&7 == lr&7
                const int csw  = ((ks * 4 + quad) ^ (lr & 7)) * 8;
                af[tm] = *(const short8*)&Acur[rowa * 64 + csw];
            }
            #pragma unroll
            for (int tn = 0; tn < 2; ++tn)
                bfx[tn] = *(const short8*)&Bsm[(nw + tn * 16 + lr) * RS + ks * 32 + quad * 8];
            #pragma unroll
            for (int tm = 0; tm < 4; ++tm)
                #pragma unroll
                for (int tn = 0; tn < 2; ++tn)
                    acc[tm][tn] = MFMA(af[tm], bfx[tn], acc[tm][tn], 0, 0, 0);
        }
        __syncthreads();   // all reads done; also drains A(kt+1) (covered)
        ushort* tmp = Acur; Acur = Anxt; Anxt = tmp;
    }

    // epilogue: D layout col=lane&15, row=quad*4+reg [verified m89/m91]
    if (OUT) {
        float* TF = (float*)SMEM;
        #pragma unroll
        for (int pass = 0; pass < 2; ++pass) {
            __syncthreads();
            if ((w >> 1) == pass) {
                #pragma unroll
                for (int tn = 0; tn < 2; ++tn) {
                    const float bval = bias[n0 + nw + tn * 16 + lr];
                    #pragma unroll
                    for (int tm = 0; tm < 4; ++tm)
                        #pragma unroll
                        for (int r = 0; r < 4; ++r)
                            TF[(tm * 16 + quad * 4 + r) * 68 + nw + tn * 16 + lr] =
                                acc[tm][tn][r] + bval;
                }
            }
            __syncthreads();
            #pragma unroll
            for (int it = 0; it < 4; ++it) {
                const int cid = it * 256 + t;
                const int row = cid >> 4, c4 = (cid & 15) * 4;
                nts16f(Fd + (size_t)(m0 + pass * 64 + row) * DIM + n0 + c4,
                       *(const float4*)&TF[row * 68 + c4]);
            }
        }
        return;
    }

    const int bb = m0 >> 10, ii0 = m0 & 1023;
    const int head = blockIdx.x & 15;
    const int bh = bb * HEADS + head;
    if (!isV) {
        #pragma unroll
        for (int tn = 0; tn < 2; ++tn) {
            const float bval = bias[n0 + nw + tn * 16 + lr];
            #pragma unroll
            for (int tm = 0; tm < 4; ++tm)
                #pragma unroll
                for (int r = 0; r < 4; ++r)
                    SMEM[(mw + tm * 16 + quad * 4 + r) * 80 + nw + tn * 16 + lr] =
                        f2b(acc[tm][tn][r] + bval);
        }
        __syncthreads();
        #pragma unroll
        for (int it = 0; it < 4; ++it) {
            const int cid = it * 256 + t;
            const int row = cid >> 3, col8 = (cid & 7) * 8;
            nts16(Qd + ((size_t)bh * SEQ + ii0 + row) * HD + col8,
                  *(const uint4*)&SMEM[row * 80 + col8]);
        }
    } else {
        #pragma unroll
        for (int tn = 0; tn < 2; ++tn) {
            const float bval = bias[n0 + nw + tn * 16 + lr];
            #pragma unroll
            for (int tm = 0; tm < 4; ++tm)
                #pragma unroll
                for (int r = 0; r < 4; ++r)
                    SMEM[(nw + tn * 16 + lr) * 144 + mw + tm * 16 + quad * 4 + r] =
                        f2b(acc[tm][tn][r] + bval);
        }
        __syncthreads();
        #pragma unroll
        for (int it = 0; it < 4; ++it) {
            const int cid = it * 256 + t;
            const int row = cid >> 4, col8 = (cid & 15) * 8;
            nts16(Vd + ((size_t)bh * HD + row) * SEQ + ii0 + col8,
                  *(const uint4*)&SMEM[row * 144 + col8]);
        }
    }
}

// ---------------------------------------------------------------------------
// MFMA flash L2-attention, i-tile 128 (r0-proven, unchanged).
// 512 blocks, XCD swizzle bh=id&63. Q bf16 [bh][n][64], Vt bf16 [bh][d][n].
// O bf16 [b][n][h*d].
// ---------------------------------------------------------------------------
__global__ __launch_bounds__(256)
void attn_mfma(const ushort* __restrict__ Q, const ushort* __restrict__ Vt,
               ushort* __restrict__ O)
{
    __shared__ __align__(16) ushort Ps[128 * RS];   // Q stage, then P [i][j]
    __shared__ __align__(16) ushort Ks[64 * RS];
    __shared__ __align__(16) ushort Vs[64 * RS];
    __shared__ float sqq[128], sqk[64];

    const int t = threadIdx.x;
    const int w = t >> 6, lane = t & 63;
    const int lr = lane & 15, quad = lane >> 4;
    const int id = blockIdx.x;
    const int bh = id & 63;            // 512 blocks: 8 i-blocks x 64 bh
    const int i0 = (id >> 6) * 128;
    const ushort* __restrict__ Qp = Q  + (size_t)bh * SEQ * HD;
    const ushort* __restrict__ Vp = Vt + (size_t)bh * HD * SEQ;

    const int sr = t >> 3, sc8 = (t & 7) * 8;

    #pragma unroll
    for (int it = 0; it < 4; ++it) {
        const int cid = it * 256 + t;
        const int r = cid >> 3, c8 = (cid & 7) * 8;
        *(uint4*)&Ps[r * RS + c8] = *(const uint4*)(Qp + (size_t)(i0 + r) * HD + c8);
    }
    __syncthreads();

    {
        const int qsub = quad & 1, half = quad >> 1;
        const int qr = w * 32 + qsub * 16 + lr, ch = half * 32;
        float s = 0.f;
        #pragma unroll
        for (int cc = 0; cc < 4; ++cc) {
            uint4 k = *(const uint4*)&Ps[qr * RS + ch + cc * 8];
            const ushort* u = (const ushort*)&k;
            #pragma unroll
            for (int e = 0; e < 8; ++e) { float f = b2f(u[e]); s += f * f; }
        }
        s += __shfl_xor(s, 32);
        if (half == 0) sqq[qr] = s;
    }
    __syncthreads();

    short8 qa[2][2];
    #pragma unroll
    for (int tm = 0; tm < 2; ++tm)
        #pragma unroll
        for (int ks = 0; ks < 2; ++ks)
            qa[tm][ks] = *(const short8*)&Ps[(w * 32 + tm * 16 + lr) * RS + ks * 32 + quad * 8];
    float sqi[2][4];
    #pragma unroll
    for (int tm = 0; tm < 2; ++tm)
        #pragma unroll
        for (int r = 0; r < 4; ++r)
            sqi[tm][r] = sqq[w * 32 + tm * 16 + quad * 4 + r];

    floatx4 oacc[2][4];
    const floatx4 fz = {0.f, 0.f, 0.f, 0.f};
    float lrow[2][4] = {};
    #pragma unroll
    for (int tm = 0; tm < 2; ++tm)
        #pragma unroll
        for (int td = 0; td < 4; ++td) oacc[tm][td] = fz;

    for (int jt = 0; jt < 16; ++jt) {
        const int j0 = jt * 64;
        __syncthreads();
        #pragma unroll
        for (int it = 0; it < 2; ++it) {
            const int r = it * 32 + sr;
            *(uint4*)&Ks[r * RS + sc8] = *(const uint4*)(Qp + (size_t)(j0 + r) * HD + sc8);
            *(uint4*)&Vs[r * RS + sc8] = *(const uint4*)(Vp + (size_t)r * SEQ + j0 + sc8);
        }
        __syncthreads();

        {
            const int jr = w * 16 + lr, ch = quad * 16;
            uint4 k1 = *(const uint4*)&Ks[jr * RS + ch];
            uint4 k2 = *(const uint4*)&Ks[jr * RS + ch + 8];
            const ushort* u1 = (const ushort*)&k1;
            const ushort* u2 = (const ushort*)&k2;
            float s = 0.f;
            #pragma unroll
            for (int cc = 0; cc < 8; ++cc) {
                float f1 = b2f(u1[cc]), f2 = b2f(u2[cc]);
                s += f1 * f1 + f2 * f2;
            }
            s += __shfl_xor(s, 16);
            s += __shfl_xor(s, 32);
            if (quad == 0) sqk[jr] = s;
        }
        __syncthreads();

        float sq4[4];
        #pragma unroll
        for (int tn = 0; tn < 4; ++tn) sq4[tn] = sqk[tn * 16 + lr];

        short8 kb[4][2];
        #pragma unroll
        for (int tn = 0; tn < 4; ++tn)
            #pragma unroll
            for (int ks = 0; ks < 2; ++ks)
                kb[tn][ks] = *(const short8*)&Ks[(tn * 16 + lr) * RS + ks * 32 + quad * 8];

        #pragma unroll
        for (int tm = 0; tm < 2; ++tm) {
            floatx4 sacc[4];
            #pragma unroll
            for (int tn = 0; tn < 4; ++tn) {
                floatx4 a = MFMA(qa[tm][0], kb[tn][0], fz, 0, 0, 0);
                sacc[tn]  = MFMA(qa[tm][1], kb[tn][1], a, 0, 0, 0);
            }
            float sc[4][4];
            #pragma unroll
            for (int tn = 0; tn < 4; ++tn) {
                const float msq = -0.125f * sq4[tn];
                #pragma unroll
                for (int r = 0; r < 4; ++r)
                    sc[tn][r] = __expf(0.25f * sacc[tn][r] + msq - 0.125f * sqi[tm][r]);
            }
            #pragma unroll
            for (int r = 0; r < 4; ++r)
                lrow[tm][r] += sc[0][r] + sc[1][r] + sc[2][r] + sc[3][r];
            #pragma unroll
            for (int tp = 0; tp < 2; ++tp)
                #pragma unroll
                for (int r = 0; r < 4; ++r) {
                    float2 fp; fp.x = sc[2 * tp][r]; fp.y = sc[2 * tp + 1][r];
                    union { __hip_bfloat162 h; unsigned u; } cv;
                    cv.h = __float22bfloat162_rn(fp);
                    const int rowb = (w * 32 + tm * 16 + quad * 4 + r) * RS + lr;
                    Ps[rowb + (2 * tp) * 16]     = (ushort)(cv.u & 0xffffu);
                    Ps[rowb + (2 * tp + 1) * 16] = (ushort)(cv.u >> 16);
                }
        }
        __syncthreads();   // P stores visible before PV fragment reads

        short8 pa[2][2], vb[4][2];
        #pragma unroll
        for (int tm = 0; tm < 2; ++tm)
            #pragma unroll
            for (int ks = 0; ks < 2; ++ks)
                pa[tm][ks] = *(const short8*)&Ps[(w * 32 + tm * 16 + lr) * RS + ks * 32 + quad * 8];
        #pragma unroll
        for (int td = 0; td < 4; ++td)
            #pragma unroll
            for (int ks = 0; ks < 2; ++ks)
                vb[td][ks] = *(const short8*)&Vs[(td * 16 + lr) * RS + ks * 32 + quad * 8];
        #pragma unroll
        for (int tm = 0; tm < 2; ++tm)
            #pragma unroll
            for (int td = 0; td < 4; ++td) {
                oacc[tm][td] = MFMA(pa[tm][0], vb[td][0], oacc[tm][td], 0, 0, 0);
                oacc[tm][td] = MFMA(pa[tm][1], vb[td][1], oacc[tm][td], 0, 0, 0);
            }
    }

    const int bb = bh >> 4, head = bh & 15;
    #pragma unroll
    for (int tm = 0; tm < 2; ++tm)
        #pragma unroll
        for (int r = 0; r < 4; ++r) {
            float l = lrow[tm][r];
            l += __shfl_xor(l, 1);
            l += __shfl_xor(l, 2);
            l += __shfl_xor(l, 4);
            l += __shfl_xor(l, 8);
            const float inv = 1.f / l;
            const int row = i0 + w * 32 + tm * 16 + quad * 4 + r;
            #pragma unroll
            for (int td = 0; td < 4; ++td) {
                nts2(O + (size_t)(bb * SEQ + row) * DIM + head * HD + td * 16 + lr,
                     f2b(oacc[tm][td][r] * inv));
            }
        }
}

extern "C" void kernel_launch(void* const* d_in, const int* in_sizes, int n_in,
                              void* d_out, int out_size, void* d_ws, size_t ws_size,
                              hipStream_t stream)
{
    const float* x  = (const float*)d_in[0];
    const float* Wq = (const float*)d_in[1];
    const float* bq = (const float*)d_in[2];
    const float* Wv = (const float*)d_in[3];
    const float* bv = (const float*)d_in[4];
    const float* Wo = (const float*)d_in[5];
    const float* bo = (const float*)d_in[6];

    // d_ws (proven 24 MB): Qh 8MB | Vt 8MB | R 8MB (xb for QV, then Oh)
    ushort* Qh = (ushort*)d_ws;
    ushort* Vt = Qh + (size_t)BATCH * HEADS * SEQ * HD;
    ushort* R  = Vt + (size_t)BATCH * HEADS * SEQ * HD;

    conv_x<<<2048, 256, 0, stream>>>(x, R);
    gemm_core<0><<<dim3(32, 32), 256, 0, stream>>>(R, Wq, bq, Wv, bv, Qh, Vt, nullptr);
    attn_mfma<<<512, 256, 0, stream>>>(Qh, Vt, R);   // Oh overwrites xb (dead)
    gemm_core<1><<<dim3(16, 32), 256, 0, stream>>>(R, Wo, bo, nullptr, nullptr,
                                                   nullptr, nullptr, (float*)d_out);
}